// Round 4
// baseline (2452.611 us; speedup 1.0000x reference)
//
#include <hip/hip_runtime.h>
#include <math.h>

#define NRAYS 4096
#define NSAMP 128
#define GSZ   128
#define VOX   (GSZ*GSZ*GSZ)
#define APPC  27
#define FCH   128
#define INW   390
#define TP    16
#define ROWP  392   // padded row stride for S_in (16B aligned)

__global__ __launch_bounds__(128)
void nerf_render(const float* __restrict__ xyz,
                 const float* __restrict__ viewdirs,
                 const float* __restrict__ dists,
                 const float* __restrict__ dgrid,
                 const float* __restrict__ agrid,
                 const float* __restrict__ w1,
                 const float* __restrict__ b1,
                 const float* __restrict__ w2,
                 const float* __restrict__ b2,
                 const float* __restrict__ w3,
                 const float* __restrict__ b3,
                 float* __restrict__ out)
{
    __shared__ int   s_base[NSAMP];
    __shared__ float s_w8[NSAMP][8];
    __shared__ float s_wts[NSAMP];
    __shared__ float s_vrow[40];          // [vdir(3), sinV(18), cosV(18)]
    __shared__ float S_in[TP][ROWP];      // mlp_in rows; later aliased as h2
    __shared__ float s_h1[TP][FCH];
    __shared__ float s_partial[TP*3];
    __shared__ float s_scanw0;

    float (* const s_h2)[FCH] = reinterpret_cast<float (*)[FCH]>(&S_in[0][0]);

    const int r    = blockIdx.x;
    const int t    = threadIdx.x;
    const int lane = t & 63;

    if (t < TP*3) s_partial[t] = 0.f;

    // ---------------- density sample + alpha + prefix-product weights --------
    {
        const int s = t;
        const float px = xyz[(r*NSAMP + s)*3 + 0];
        const float py = xyz[(r*NSAMP + s)*3 + 1];
        const float pz = xyz[(r*NSAMP + s)*3 + 2];
        float fx = (px + 1.0f) * 63.5f;
        float fy = (py + 1.0f) * 63.5f;
        float fz = (pz + 1.0f) * 63.5f;
        int x0 = (int)floorf(fx); x0 = min(max(x0, 0), GSZ-2);
        int y0 = (int)floorf(fy); y0 = min(max(y0, 0), GSZ-2);
        int z0 = (int)floorf(fz); z0 = min(max(z0, 0), GSZ-2);
        float wx = fx - (float)x0, wy = fy - (float)y0, wz = fz - (float)z0;
        float ux = 1.f - wx, uy = 1.f - wy, uz = 1.f - wz;
        int base = (z0*GSZ + y0)*GSZ + x0;
        s_base[s] = base;
        float w000 = uz*uy*ux, w001 = uz*uy*wx, w010 = uz*wy*ux, w011 = uz*wy*wx;
        float w100 = wz*uy*ux, w101 = wz*uy*wx, w110 = wz*wy*ux, w111 = wz*wy*wx;
        s_w8[s][0] = w000; s_w8[s][1] = w001; s_w8[s][2] = w010; s_w8[s][3] = w011;
        s_w8[s][4] = w100; s_w8[s][5] = w101; s_w8[s][6] = w110; s_w8[s][7] = w111;

        const float* dg = dgrid + base;
        float dsum = w000*dg[0]            + w001*dg[1]
                   + w010*dg[GSZ]          + w011*dg[GSZ+1]
                   + w100*dg[GSZ*GSZ]      + w101*dg[GSZ*GSZ+1]
                   + w110*dg[GSZ*GSZ+GSZ]  + w111*dg[GSZ*GSZ+GSZ+1];
        float sf    = dsum - 10.0f;
        float sigma = fmaxf(sf, 0.f) + log1pf(expf(-fabsf(sf)));   // softplus
        float alpha = 1.f - expf(-sigma * dists[r*NSAMP + s] * 25.0f);
        float v     = 1.f - alpha + 1e-10f;

        // inclusive multiplicative scan within wave
        float scan = v;
        #pragma unroll
        for (int off = 1; off < 64; off <<= 1) {
            float o = __shfl_up(scan, off, 64);
            if (lane >= off) scan *= o;
        }
        if (t == 63) s_scanw0 = scan;
        __syncthreads();
        float prev = __shfl_up(scan, 1, 64);
        float excl;
        if (t < 64) excl = (lane == 0) ? 1.0f      : prev;
        else        excl = (lane == 0) ? s_scanw0  : prev * s_scanw0;
        s_wts[s] = alpha * excl;
    }

    // ---------------- per-ray view-dir PE (constant over samples) ------------
    if (t < 21) {
        if (t < 3) {
            s_vrow[t] = viewdirs[r*3 + t];
        } else {
            int i = t - 3;               // 0..17
            int d = i / 6, f = i - 6*d;
            float vd = viewdirs[r*3 + d];
            float sv, cv;
            sincosf(vd * (float)(1 << f), &sv, &cv);
            s_vrow[3  + i] = sv;
            s_vrow[21 + i] = cv;
        }
    }
    __syncthreads();

    // ---------------- tile loop over samples ---------------------------------
    for (int s0 = 0; s0 < NSAMP; s0 += TP) {
        // A: appearance gather -> S_in[p][0..26]
        for (int idx = t; idx < TP*APPC; idx += 128) {
            int p = idx / APPC;
            int c = idx - p*APPC;
            int s = s0 + p;
            const float* ag = agrid + (size_t)c*VOX + s_base[s];
            const float* w8 = s_w8[s];
            float val = w8[0]*ag[0]           + w8[1]*ag[1]
                      + w8[2]*ag[GSZ]         + w8[3]*ag[GSZ+1]
                      + w8[4]*ag[GSZ*GSZ]     + w8[5]*ag[GSZ*GSZ+1]
                      + w8[6]*ag[GSZ*GSZ+GSZ] + w8[7]*ag[GSZ*GSZ+GSZ+1];
            S_in[p][c] = val;
        }
        // fill vdirs + view PE into each row
        for (int idx = t; idx < TP*39; idx += 128) {
            int p = idx / 39;
            int j = idx - p*39;
            S_in[p][(j < 3) ? (27 + j) : (351 + j)] = s_vrow[j];
        }
        __syncthreads();

        // B: feature PE -> S_in[p][30..353]
        for (int idx = t; idx < TP*162; idx += 128) {
            int p   = idx / 162;
            int rem = idx - p*162;
            int d = rem / 6, f = rem - 6*d;
            float v = S_in[p][d];
            float sv, cv;
            sincosf(v * (float)(1 << f), &sv, &cv);
            S_in[p][30  + rem] = sv;
            S_in[p][192 + rem] = cv;
        }
        __syncthreads();

        // C: layer1 (390 -> 128), thread t owns output channel j=t
        {
            const int j = t;
            float acc[TP];
            const float bj = b1[j];
            #pragma unroll
            for (int p = 0; p < TP; p++) acc[p] = bj;
            int k = 0;
            for (; k + 4 <= INW; k += 4) {
                float wk0 = w1[(k+0)*FCH + j];
                float wk1 = w1[(k+1)*FCH + j];
                float wk2 = w1[(k+2)*FCH + j];
                float wk3 = w1[(k+3)*FCH + j];
                #pragma unroll
                for (int p = 0; p < TP; p++) {
                    const float4 sv = *reinterpret_cast<const float4*>(&S_in[p][k]);
                    acc[p] = fmaf(sv.x, wk0, acc[p]);
                    acc[p] = fmaf(sv.y, wk1, acc[p]);
                    acc[p] = fmaf(sv.z, wk2, acc[p]);
                    acc[p] = fmaf(sv.w, wk3, acc[p]);
                }
            }
            for (; k < INW; k++) {
                float wk = w1[k*FCH + j];
                #pragma unroll
                for (int p = 0; p < TP; p++)
                    acc[p] = fmaf(S_in[p][k], wk, acc[p]);
            }
            #pragma unroll
            for (int p = 0; p < TP; p++) s_h1[p][j] = fmaxf(acc[p], 0.f);
        }
        __syncthreads();

        // D: layer2 (128 -> 128), writes h2 (aliases S_in — S_in is dead now)
        {
            const int j = t;
            float acc[TP];
            const float bj = b2[j];
            #pragma unroll
            for (int p = 0; p < TP; p++) acc[p] = bj;
            for (int k = 0; k < FCH; k += 4) {
                float wk0 = w2[(k+0)*FCH + j];
                float wk1 = w2[(k+1)*FCH + j];
                float wk2 = w2[(k+2)*FCH + j];
                float wk3 = w2[(k+3)*FCH + j];
                #pragma unroll
                for (int p = 0; p < TP; p++) {
                    const float4 hv = *reinterpret_cast<const float4*>(&s_h1[p][k]);
                    acc[p] = fmaf(hv.x, wk0, acc[p]);
                    acc[p] = fmaf(hv.y, wk1, acc[p]);
                    acc[p] = fmaf(hv.z, wk2, acc[p]);
                    acc[p] = fmaf(hv.w, wk3, acc[p]);
                }
            }
            #pragma unroll
            for (int p = 0; p < TP; p++) s_h2[p][j] = fmaxf(acc[p], 0.f);
        }
        __syncthreads();

        // E: layer3 (128 -> 3) + sigmoid + weighted accumulate
        if (t < TP*3) {
            int p = t / 3, c = t - 3*p;
            float acc = b3[c];
            for (int k = 0; k < FCH; k++)
                acc = fmaf(s_h2[p][k], w3[k*3 + c], acc);
            float rgb = 1.0f / (1.0f + expf(-acc));
            s_partial[t] += s_wts[s0 + p] * rgb;
        }
        __syncthreads();
    }

    if (t < 3) {
        float sum = 0.f;
        #pragma unroll
        for (int p = 0; p < TP; p++) sum += s_partial[p*3 + t];
        out[r*3 + t] = sum;
    }
}

extern "C" void kernel_launch(void* const* d_in, const int* in_sizes, int n_in,
                              void* d_out, int out_size, void* d_ws, size_t ws_size,
                              hipStream_t stream) {
    const float* xyz      = (const float*)d_in[0];
    const float* viewdirs = (const float*)d_in[1];
    const float* dists    = (const float*)d_in[2];
    const float* dgrid    = (const float*)d_in[3];
    const float* agrid    = (const float*)d_in[4];
    const float* w1       = (const float*)d_in[5];
    const float* b1       = (const float*)d_in[6];
    const float* w2       = (const float*)d_in[7];
    const float* b2       = (const float*)d_in[8];
    const float* w3       = (const float*)d_in[9];
    const float* b3       = (const float*)d_in[10];
    float* out = (float*)d_out;

    hipLaunchKernelGGL(nerf_render, dim3(NRAYS), dim3(128), 0, stream,
                       xyz, viewdirs, dists, dgrid, agrid,
                       w1, b1, w2, b2, w3, b3, out);
}

// Round 6
// 2180.292 us; speedup vs baseline: 1.1249x; 1.1249x over previous
//
#include <hip/hip_runtime.h>
#include <math.h>

#define NRAYS  4096
#define NSAMP  128
#define GSZ    128
#define VOX    (GSZ*GSZ*GSZ)
#define APPC   27
#define FCH    128
#define INW    390
#define TP     16
#define ROWP   392   // padded row stride for S_in (floats)
#define H2S    132   // h2 row stride (floats) — breaks 16-way bank conflict in phase E
#define VOXPAD 32    // ushort elems per voxel in transposed grid (64 B/voxel)

// ---- pre-pass: app_grid [27][128^3] f32  ->  d_ws [128^3][32] bf16 ----------
__global__ __launch_bounds__(256)
void transpose_app(const float* __restrict__ ag, ushort* __restrict__ out)
{
    const int v = blockIdx.x * 256 + threadIdx.x;
    ushort h[VOXPAD];
    #pragma unroll
    for (int c = 0; c < APPC; c++) {
        union { float f; unsigned u; } x;
        x.f = ag[(size_t)c * VOX + v];
        unsigned u = x.u;
        u = (u + 0x7FFFu + ((u >> 16) & 1u)) >> 16;   // RNE to bf16
        h[c] = (ushort)u;
    }
    #pragma unroll
    for (int c = APPC; c < VOXPAD; c++) h[c] = 0;
    uint4* o = reinterpret_cast<uint4*>(out + (size_t)v * VOXPAD);
    #pragma unroll
    for (int i = 0; i < 4; i++) {
        uint4 q;
        q.x = (unsigned)h[8*i+0] | ((unsigned)h[8*i+1] << 16);
        q.y = (unsigned)h[8*i+2] | ((unsigned)h[8*i+3] << 16);
        q.z = (unsigned)h[8*i+4] | ((unsigned)h[8*i+5] << 16);
        q.w = (unsigned)h[8*i+6] | ((unsigned)h[8*i+7] << 16);
        o[i] = q;
    }
}

template<bool TR>
__global__ __launch_bounds__(128)
void nerf_render(const float* __restrict__ xyz,
                 const float* __restrict__ viewdirs,
                 const float* __restrict__ dists,
                 const float* __restrict__ dgrid,
                 const float* __restrict__ agrid,
                 const ushort* __restrict__ agridT,
                 const float* __restrict__ w1,
                 const float* __restrict__ b1,
                 const float* __restrict__ w2,
                 const float* __restrict__ b2,
                 const float* __restrict__ w3,
                 const float* __restrict__ b3,
                 float* __restrict__ out)
{
    __shared__ int   s_base[NSAMP];
    __shared__ float s_w8[NSAMP][8];
    __shared__ float s_wts[NSAMP];
    __shared__ float s_vrow[40];          // [vdir(3), sinV(18), cosV(18)]
    __shared__ float S_in[TP][ROWP];      // mlp_in rows; later aliased as h2 (stride H2S)
    __shared__ float s_h1[TP][FCH];
    __shared__ float s_partial[TP*3];
    __shared__ float s_scanw0;

    float* const s_h2f = &S_in[0][0];     // h2 view: s_h2f[p*H2S + j]

    const int r    = blockIdx.x;
    const int t    = threadIdx.x;
    const int lane = t & 63;

    if (t < TP*3) s_partial[t] = 0.f;

    // ---------------- density sample + alpha + prefix-product weights --------
    {
        const int s = t;
        const float px = xyz[(r*NSAMP + s)*3 + 0];
        const float py = xyz[(r*NSAMP + s)*3 + 1];
        const float pz = xyz[(r*NSAMP + s)*3 + 2];
        float fx = (px + 1.0f) * 63.5f;
        float fy = (py + 1.0f) * 63.5f;
        float fz = (pz + 1.0f) * 63.5f;
        int x0 = (int)floorf(fx); x0 = min(max(x0, 0), GSZ-2);
        int y0 = (int)floorf(fy); y0 = min(max(y0, 0), GSZ-2);
        int z0 = (int)floorf(fz); z0 = min(max(z0, 0), GSZ-2);
        float wx = fx - (float)x0, wy = fy - (float)y0, wz = fz - (float)z0;
        float ux = 1.f - wx, uy = 1.f - wy, uz = 1.f - wz;
        int base = (z0*GSZ + y0)*GSZ + x0;
        s_base[s] = base;
        float w000 = uz*uy*ux, w001 = uz*uy*wx, w010 = uz*wy*ux, w011 = uz*wy*wx;
        float w100 = wz*uy*ux, w101 = wz*uy*wx, w110 = wz*wy*ux, w111 = wz*wy*wx;
        s_w8[s][0] = w000; s_w8[s][1] = w001; s_w8[s][2] = w010; s_w8[s][3] = w011;
        s_w8[s][4] = w100; s_w8[s][5] = w101; s_w8[s][6] = w110; s_w8[s][7] = w111;

        const float* dg = dgrid + base;
        float dsum = w000*dg[0]            + w001*dg[1]
                   + w010*dg[GSZ]          + w011*dg[GSZ+1]
                   + w100*dg[GSZ*GSZ]      + w101*dg[GSZ*GSZ+1]
                   + w110*dg[GSZ*GSZ+GSZ]  + w111*dg[GSZ*GSZ+GSZ+1];
        float sf    = dsum - 10.0f;
        float sigma = fmaxf(sf, 0.f) + log1pf(expf(-fabsf(sf)));   // softplus
        float alpha = 1.f - expf(-sigma * dists[r*NSAMP + s] * 25.0f);
        float v     = 1.f - alpha + 1e-10f;

        // inclusive multiplicative scan within wave
        float scan = v;
        #pragma unroll
        for (int off = 1; off < 64; off <<= 1) {
            float o = __shfl_up(scan, off, 64);
            if (lane >= off) scan *= o;
        }
        if (t == 63) s_scanw0 = scan;
        __syncthreads();
        float prev = __shfl_up(scan, 1, 64);
        float excl;
        if (t < 64) excl = (lane == 0) ? 1.0f      : prev;
        else        excl = (lane == 0) ? s_scanw0  : prev * s_scanw0;
        s_wts[s] = alpha * excl;
    }

    // ---------------- per-ray view-dir PE (constant over samples) ------------
    if (t < 21) {
        if (t < 3) {
            s_vrow[t] = viewdirs[r*3 + t];
        } else {
            int i = t - 3;               // 0..17
            int d = i / 6, f = i - 6*d;
            float vd = viewdirs[r*3 + d];
            float sv, cv;
            sincosf(vd * (float)(1 << f), &sv, &cv);
            s_vrow[3  + i] = sv;
            s_vrow[21 + i] = cv;
        }
    }
    __syncthreads();

    // ---------------- tile loop over samples ---------------------------------
    for (int s0 = 0; s0 < NSAMP; s0 += TP) {
        // A: appearance gather -> S_in[p][0..26]
        if (TR) {
            // 128 lanes = 16 points x 8 taps; 1 voxel = 1 aligned 64B line
            const int p   = t >> 3;
            const int tap = t & 7;
            const int s   = s0 + p;
            const int dz  = tap >> 2, dy = (tap >> 1) & 1, dx = tap & 1;
            const int vox = s_base[s] + dz*GSZ*GSZ + dy*GSZ + dx;
            const float wt = s_w8[s][tap];
            const ushort* vp = agridT + (size_t)vox * VOXPAD;
            const uint4 a0 = *reinterpret_cast<const uint4*>(vp);
            const uint4 a1 = *reinterpret_cast<const uint4*>(vp + 8);
            const uint4 a2 = *reinterpret_cast<const uint4*>(vp + 16);
            const uint2 a3 = *reinterpret_cast<const uint2*>(vp + 24);
            unsigned dw[14] = {a0.x,a0.y,a0.z,a0.w, a1.x,a1.y,a1.z,a1.w,
                               a2.x,a2.y,a2.z,a2.w, a3.x,a3.y};
            float f[27];
            #pragma unroll
            for (int i = 0; i < 14; i++) {
                float lo = __uint_as_float(dw[i] << 16);
                f[2*i] = lo * wt;
                if (2*i + 1 < 27) {
                    float hi = __uint_as_float(dw[i] & 0xffff0000u);
                    f[2*i+1] = hi * wt;
                }
            }
            #pragma unroll
            for (int m = 1; m < 8; m <<= 1) {
                #pragma unroll
                for (int c = 0; c < 27; c++)
                    f[c] += __shfl_xor(f[c], m, 64);
            }
            for (int c = tap; c < APPC; c += 8) S_in[p][c] = f[c];
        } else {
            for (int idx = t; idx < TP*APPC; idx += 128) {
                int p = idx / APPC;
                int c = idx - p*APPC;
                int s = s0 + p;
                const float* ag = agrid + (size_t)c*VOX + s_base[s];
                const float* w8 = s_w8[s];
                float val = w8[0]*ag[0]           + w8[1]*ag[1]
                          + w8[2]*ag[GSZ]         + w8[3]*ag[GSZ+1]
                          + w8[4]*ag[GSZ*GSZ]     + w8[5]*ag[GSZ*GSZ+1]
                          + w8[6]*ag[GSZ*GSZ+GSZ] + w8[7]*ag[GSZ*GSZ+GSZ+1];
                S_in[p][c] = val;
            }
        }
        // fill vdirs + view PE into each row
        for (int idx = t; idx < TP*39; idx += 128) {
            int p = idx / 39;
            int j = idx - p*39;
            S_in[p][(j < 3) ? (27 + j) : (351 + j)] = s_vrow[j];
        }
        __syncthreads();

        // B: feature PE -> S_in[p][30..353]
        for (int idx = t; idx < TP*162; idx += 128) {
            int p   = idx / 162;
            int rem = idx - p*162;
            int d = rem / 6, f = rem - 6*d;
            float v = S_in[p][d];
            float sv, cv;
            __sincosf(v * (float)(1 << f), &sv, &cv);
            S_in[p][30  + rem] = sv;
            S_in[p][192 + rem] = cv;
        }
        __syncthreads();

        // C: layer1 (390 -> 128), thread t owns output channel j=t
        {
            const int j = t;
            float acc[TP];
            const float bj = b1[j];
            #pragma unroll
            for (int p = 0; p < TP; p++) acc[p] = bj;
            int k = 0;
            for (; k + 4 <= INW; k += 4) {
                float wk0 = w1[(k+0)*FCH + j];
                float wk1 = w1[(k+1)*FCH + j];
                float wk2 = w1[(k+2)*FCH + j];
                float wk3 = w1[(k+3)*FCH + j];
                #pragma unroll
                for (int p = 0; p < TP; p++) {
                    const float4 sv = *reinterpret_cast<const float4*>(&S_in[p][k]);
                    acc[p] = fmaf(sv.x, wk0, acc[p]);
                    acc[p] = fmaf(sv.y, wk1, acc[p]);
                    acc[p] = fmaf(sv.z, wk2, acc[p]);
                    acc[p] = fmaf(sv.w, wk3, acc[p]);
                }
            }
            for (; k < INW; k++) {
                float wk = w1[k*FCH + j];
                #pragma unroll
                for (int p = 0; p < TP; p++)
                    acc[p] = fmaf(S_in[p][k], wk, acc[p]);
            }
            #pragma unroll
            for (int p = 0; p < TP; p++) s_h1[p][j] = fmaxf(acc[p], 0.f);
        }
        __syncthreads();

        // D: layer2 (128 -> 128), writes h2 (aliases dead S_in, stride H2S)
        {
            const int j = t;
            float acc[TP];
            const float bj = b2[j];
            #pragma unroll
            for (int p = 0; p < TP; p++) acc[p] = bj;
            for (int k = 0; k < FCH; k += 4) {
                float wk0 = w2[(k+0)*FCH + j];
                float wk1 = w2[(k+1)*FCH + j];
                float wk2 = w2[(k+2)*FCH + j];
                float wk3 = w2[(k+3)*FCH + j];
                #pragma unroll
                for (int p = 0; p < TP; p++) {
                    const float4 hv = *reinterpret_cast<const float4*>(&s_h1[p][k]);
                    acc[p] = fmaf(hv.x, wk0, acc[p]);
                    acc[p] = fmaf(hv.y, wk1, acc[p]);
                    acc[p] = fmaf(hv.z, wk2, acc[p]);
                    acc[p] = fmaf(hv.w, wk3, acc[p]);
                }
            }
            #pragma unroll
            for (int p = 0; p < TP; p++) s_h2f[p*H2S + j] = fmaxf(acc[p], 0.f);
        }
        __syncthreads();

        // E: layer3 (128 -> 3) + sigmoid + weighted accumulate
        if (t < TP*3) {
            int p = t / 3, c = t - 3*p;
            float acc = b3[c];
            for (int k = 0; k < FCH; k++)
                acc = fmaf(s_h2f[p*H2S + k], w3[k*3 + c], acc);
            float rgb = 1.0f / (1.0f + expf(-acc));
            s_partial[t] += s_wts[s0 + p] * rgb;
        }
        __syncthreads();
    }

    if (t < 3) {
        float sum = 0.f;
        #pragma unroll
        for (int p = 0; p < TP; p++) sum += s_partial[p*3 + t];
        out[r*3 + t] = sum;
    }
}

extern "C" void kernel_launch(void* const* d_in, const int* in_sizes, int n_in,
                              void* d_out, int out_size, void* d_ws, size_t ws_size,
                              hipStream_t stream) {
    const float* xyz      = (const float*)d_in[0];
    const float* viewdirs = (const float*)d_in[1];
    const float* dists    = (const float*)d_in[2];
    const float* dgrid    = (const float*)d_in[3];
    const float* agrid    = (const float*)d_in[4];
    const float* w1       = (const float*)d_in[5];
    const float* b1       = (const float*)d_in[6];
    const float* w2       = (const float*)d_in[7];
    const float* b2       = (const float*)d_in[8];
    const float* w3       = (const float*)d_in[9];
    const float* b3       = (const float*)d_in[10];
    float* out = (float*)d_out;

    const size_t need = (size_t)VOX * VOXPAD * sizeof(ushort);  // 134 MB
    if (ws_size >= need) {
        ushort* agT = (ushort*)d_ws;
        hipLaunchKernelGGL(transpose_app, dim3(VOX/256), dim3(256), 0, stream,
                           agrid, agT);
        hipLaunchKernelGGL((nerf_render<true>), dim3(NRAYS), dim3(128), 0, stream,
                           xyz, viewdirs, dists, dgrid, agrid, agT,
                           w1, b1, w2, b2, w3, b3, out);
    } else {
        hipLaunchKernelGGL((nerf_render<false>), dim3(NRAYS), dim3(128), 0, stream,
                           xyz, viewdirs, dists, dgrid, agrid, (const ushort*)d_ws,
                           w1, b1, w2, b2, w3, b3, out);
    }
}

// Round 9
// 1209.590 us; speedup vs baseline: 2.0276x; 1.8025x over previous
//
#include <hip/hip_runtime.h>
#include <math.h>

#define NRAYS  4096
#define NSAMP  128
#define GSZ    128
#define VOX    (GSZ*GSZ*GSZ)
#define APPC   27
#define FCH    128
#define INW    390
#define K1PAD  416   // 13 K-steps of 32
#define TP     32    // samples per tile
#define SIP    424   // S_in row stride (ushort) -> 848 B, bank-rotating
#define H1S    136   // h1 row stride (ushort) -> 272 B
#define H2S    132   // h2 row stride (float)
#define VOXPAD 32    // ushort per voxel in transposed grid (64 B)

typedef __attribute__((ext_vector_type(8))) short bf16x8;
typedef __attribute__((ext_vector_type(4))) float f32x4;

#define MFMA16(a, b, c) __builtin_amdgcn_mfma_f32_16x16x32_bf16((a), (b), (c), 0, 0, 0)

__device__ inline ushort f2b(float f) {            // RNE f32 -> bf16
    union { float f; unsigned u; } x; x.f = f;
    unsigned u = x.u;
    u = (u + 0x7FFFu + ((u >> 16) & 1u)) >> 16;
    return (ushort)u;
}
__device__ inline float b2f(ushort h) {
    return __uint_as_float(((unsigned)h) << 16);
}

// ---- pre-pass: app_grid [27][128^3] f32 -> d_ws [128^3][32] bf16 ------------
__global__ __launch_bounds__(256)
void transpose_app(const float* __restrict__ ag, ushort* __restrict__ out)
{
    const int v = blockIdx.x * 256 + threadIdx.x;
    ushort h[VOXPAD];
    #pragma unroll
    for (int c = 0; c < APPC; c++)
        h[c] = f2b(ag[(size_t)c * VOX + v]);
    #pragma unroll
    for (int c = APPC; c < VOXPAD; c++) h[c] = 0;
    uint4* o = reinterpret_cast<uint4*>(out + (size_t)v * VOXPAD);
    #pragma unroll
    for (int i = 0; i < 4; i++) {
        uint4 q;
        q.x = (unsigned)h[8*i+0] | ((unsigned)h[8*i+1] << 16);
        q.y = (unsigned)h[8*i+2] | ((unsigned)h[8*i+3] << 16);
        q.z = (unsigned)h[8*i+4] | ((unsigned)h[8*i+5] << 16);
        q.w = (unsigned)h[8*i+6] | ((unsigned)h[8*i+7] << 16);
        o[i] = q;
    }
}

// B-fragment for mfma_f32_16x16x32_bf16 from row-major f32 W[k][n] (ld = n-dim).
// Lane l supplies B[kbase + j][n], j=0..7 (kbase already includes (l>>4)*8).
__device__ inline bf16x8 load_b_frag(const float* __restrict__ W, int ld,
                                     int kbase, int n, int kmax)
{
    union { uint4 u; bf16x8 v; } cv;
    unsigned* pr = &cv.u.x;
    #pragma unroll
    for (int q = 0; q < 4; q++) {
        const int ka = kbase + 2*q, kb = ka + 1;
        const float fa = (ka < kmax) ? W[ka*ld + n] : 0.f;
        const float fb = (kb < kmax) ? W[kb*ld + n] : 0.f;
        pr[q] = (unsigned)f2b(fa) | ((unsigned)f2b(fb) << 16);
    }
    return cv.v;
}

__global__ __launch_bounds__(256)
void nerf_render_mfma(const float* __restrict__ xyz,
                      const float* __restrict__ viewdirs,
                      const float* __restrict__ dists,
                      const float* __restrict__ dgrid,
                      const ushort* __restrict__ agridT,
                      const float* __restrict__ w1,
                      const float* __restrict__ b1,
                      const float* __restrict__ w2,
                      const float* __restrict__ b2,
                      const float* __restrict__ w3,
                      const float* __restrict__ b3,
                      float* __restrict__ out)
{
    __shared__ __align__(16) ushort S_in[TP][SIP];   // bf16 mlp_in rows
    __shared__ __align__(16) ushort s_h1[TP][H1S];   // bf16 h1
    __shared__ float  s_h2[TP][H2S];                 // f32 h2 (layer3 precision)
    __shared__ int    s_base[NSAMP];
    __shared__ float  s_w8[NSAMP][8];
    __shared__ float  s_wts[NSAMP];
    __shared__ ushort s_vrow[40];                    // bf16 [vdir3|sinV18|cosV18]
    __shared__ float  s_partial[TP*3];
    __shared__ float  s_scanw0;

    const int r    = blockIdx.x;
    const int t    = threadIdx.x;
    const int lane = t & 63;

    // zero S_in once (K pad 390..415 must be finite-zero for MFMA)
    for (int i = t; i < TP*SIP/2; i += 256)
        reinterpret_cast<unsigned*>(&S_in[0][0])[i] = 0u;
    if (t < TP*3) s_partial[t] = 0.f;

    // ---------------- density + alpha + transmittance weights ---------------
    {
        const int s = t & 127;                 // waves 2,3 duplicate (benign)
        const float px = xyz[(r*NSAMP + s)*3 + 0];
        const float py = xyz[(r*NSAMP + s)*3 + 1];
        const float pz = xyz[(r*NSAMP + s)*3 + 2];
        float fx = (px + 1.0f) * 63.5f;
        float fy = (py + 1.0f) * 63.5f;
        float fz = (pz + 1.0f) * 63.5f;
        int x0 = (int)floorf(fx); x0 = min(max(x0, 0), GSZ-2);
        int y0 = (int)floorf(fy); y0 = min(max(y0, 0), GSZ-2);
        int z0 = (int)floorf(fz); z0 = min(max(z0, 0), GSZ-2);
        float wx = fx - (float)x0, wy = fy - (float)y0, wz = fz - (float)z0;
        float ux = 1.f - wx, uy = 1.f - wy, uz = 1.f - wz;
        int base = (z0*GSZ + y0)*GSZ + x0;
        float w000 = uz*uy*ux, w001 = uz*uy*wx, w010 = uz*wy*ux, w011 = uz*wy*wx;
        float w100 = wz*uy*ux, w101 = wz*uy*wx, w110 = wz*wy*ux, w111 = wz*wy*wx;
        if (t < 128) {
            s_base[s] = base;
            s_w8[s][0] = w000; s_w8[s][1] = w001; s_w8[s][2] = w010; s_w8[s][3] = w011;
            s_w8[s][4] = w100; s_w8[s][5] = w101; s_w8[s][6] = w110; s_w8[s][7] = w111;
        }
        const float* dg = dgrid + base;
        float dsum = w000*dg[0]            + w001*dg[1]
                   + w010*dg[GSZ]          + w011*dg[GSZ+1]
                   + w100*dg[GSZ*GSZ]      + w101*dg[GSZ*GSZ+1]
                   + w110*dg[GSZ*GSZ+GSZ]  + w111*dg[GSZ*GSZ+GSZ+1];
        float sf    = dsum - 10.0f;
        float sigma = fmaxf(sf, 0.f) + log1pf(expf(-fabsf(sf)));   // softplus
        float alpha = 1.f - expf(-sigma * dists[r*NSAMP + s] * 25.0f);
        float v     = 1.f - alpha + 1e-10f;

        float scan = v;                     // inclusive multiplicative scan
        #pragma unroll
        for (int off = 1; off < 64; off <<= 1) {
            float o = __shfl_up(scan, off, 64);
            if (lane >= off) scan *= o;
        }
        if ((t & 127) == 63) s_scanw0 = scan;
        __syncthreads();
        float prev = __shfl_up(scan, 1, 64);
        float excl;
        if ((t & 127) < 64) excl = (lane == 0) ? 1.0f     : prev;
        else                excl = (lane == 0) ? s_scanw0 : prev * s_scanw0;
        if (t < 128) s_wts[s] = alpha * excl;
    }

    // ---------------- per-ray view-dir PE (bf16) -----------------------------
    if (t < 21) {
        if (t < 3) {
            s_vrow[t] = f2b(viewdirs[r*3 + t]);
        } else {
            int i = t - 3;               // 0..17
            int d = i / 6, f = i - 6*d;
            float vd = viewdirs[r*3 + d];
            float sv, cv;
            sincosf(vd * (float)(1 << f), &sv, &cv);
            s_vrow[3  + i] = f2b(sv);
            s_vrow[21 + i] = f2b(cv);
        }
    }
    __syncthreads();

    // ---------------- tile loop: 4 tiles of 32 samples -----------------------
    for (int s0 = 0; s0 < NSAMP; s0 += TP) {
        // A: appearance gather (32 pts x 8 taps = 256 lanes)
        {
            const int p   = t >> 3;
            const int tap = t & 7;
            const int s   = s0 + p;
            const int dz  = tap >> 2, dy = (tap >> 1) & 1, dx = tap & 1;
            const int vox = s_base[s] + dz*GSZ*GSZ + dy*GSZ + dx;
            const float wt = s_w8[s][tap];
            const ushort* vp = agridT + (size_t)vox * VOXPAD;
            const uint4 a0 = *reinterpret_cast<const uint4*>(vp);
            const uint4 a1 = *reinterpret_cast<const uint4*>(vp + 8);
            const uint4 a2 = *reinterpret_cast<const uint4*>(vp + 16);
            const uint2 a3 = *reinterpret_cast<const uint2*>(vp + 24);
            unsigned dw[14] = {a0.x,a0.y,a0.z,a0.w, a1.x,a1.y,a1.z,a1.w,
                               a2.x,a2.y,a2.z,a2.w, a3.x,a3.y};
            float f[27];
            #pragma unroll
            for (int i = 0; i < 14; i++) {
                f[2*i] = __uint_as_float(dw[i] << 16) * wt;
                if (2*i + 1 < 27)
                    f[2*i+1] = __uint_as_float(dw[i] & 0xffff0000u) * wt;
            }
            #pragma unroll
            for (int m = 1; m < 8; m <<= 1) {
                #pragma unroll
                for (int c = 0; c < 27; c++)
                    f[c] += __shfl_xor(f[c], m, 64);
            }
            #pragma unroll
            for (int c = 0; c < APPC; c++)          // static idx, predicated
                if ((c & 7) == tap) S_in[p][c] = f2b(f[c]);
        }
        // vdir + view-PE fill
        for (int idx = t; idx < TP*39; idx += 256) {
            int p = idx / 39, j = idx - p*39;
            S_in[p][(j < 3) ? (27 + j) : (351 + j)] = s_vrow[j];
        }
        __syncthreads();

        // B: feature PE
        for (int idx = t; idx < TP*162; idx += 256) {
            int p   = idx / 162;
            int rem = idx - p*162;
            int d = rem / 6, f = rem - 6*d;
            float v = b2f(S_in[p][d]);
            float sv, cv;
            __sincosf(v * (float)(1 << f), &sv, &cv);
            S_in[p][30  + rem] = f2b(sv);
            S_in[p][192 + rem] = f2b(cv);
        }
        __syncthreads();

        const int wv = t >> 6;
        const int mt = wv & 1, nq = wv >> 1;
        const int arow  = mt*16 + (lane & 15);
        const int kg    = (lane >> 4) * 8;
        const int ncol  = lane & 15;
        const int mbase = mt*16 + (lane >> 4)*4;

        // C: layer1  [32x416] @ [416x128] -> h1 (bf16)
        {
            f32x4 acc0 = {0.f,0.f,0.f,0.f}, acc1 = {0.f,0.f,0.f,0.f};
            f32x4 acc2 = {0.f,0.f,0.f,0.f}, acc3 = {0.f,0.f,0.f,0.f};
            const int n0 = (nq*4+0)*16 + ncol, n1 = (nq*4+1)*16 + ncol;
            const int n2 = (nq*4+2)*16 + ncol, n3 = (nq*4+3)*16 + ncol;
            for (int ks = 0; ks < 13; ks++) {
                const int k0 = ks*32 + kg;
                bf16x8 a = *reinterpret_cast<const bf16x8*>(&S_in[arow][k0]);
                acc0 = MFMA16(a, load_b_frag(w1, FCH, k0, n0, INW), acc0);
                acc1 = MFMA16(a, load_b_frag(w1, FCH, k0, n1, INW), acc1);
                acc2 = MFMA16(a, load_b_frag(w1, FCH, k0, n2, INW), acc2);
                acc3 = MFMA16(a, load_b_frag(w1, FCH, k0, n3, INW), acc3);
            }
            const float bn0 = b1[n0], bn1 = b1[n1], bn2 = b1[n2], bn3 = b1[n3];
            #pragma unroll
            for (int q = 0; q < 4; q++) {
                s_h1[mbase + q][n0] = f2b(fmaxf(acc0[q] + bn0, 0.f));
                s_h1[mbase + q][n1] = f2b(fmaxf(acc1[q] + bn1, 0.f));
                s_h1[mbase + q][n2] = f2b(fmaxf(acc2[q] + bn2, 0.f));
                s_h1[mbase + q][n3] = f2b(fmaxf(acc3[q] + bn3, 0.f));
            }
        }
        __syncthreads();

        // D: layer2  [32x128] @ [128x128] -> h2 (f32)
        {
            f32x4 acc0 = {0.f,0.f,0.f,0.f}, acc1 = {0.f,0.f,0.f,0.f};
            f32x4 acc2 = {0.f,0.f,0.f,0.f}, acc3 = {0.f,0.f,0.f,0.f};
            const int n0 = (nq*4+0)*16 + ncol, n1 = (nq*4+1)*16 + ncol;
            const int n2 = (nq*4+2)*16 + ncol, n3 = (nq*4+3)*16 + ncol;
            #pragma unroll
            for (int ks = 0; ks < 4; ks++) {
                const int k0 = ks*32 + kg;
                bf16x8 a = *reinterpret_cast<const bf16x8*>(&s_h1[arow][k0]);
                acc0 = MFMA16(a, load_b_frag(w2, FCH, k0, n0, FCH), acc0);
                acc1 = MFMA16(a, load_b_frag(w2, FCH, k0, n1, FCH), acc1);
                acc2 = MFMA16(a, load_b_frag(w2, FCH, k0, n2, FCH), acc2);
                acc3 = MFMA16(a, load_b_frag(w2, FCH, k0, n3, FCH), acc3);
            }
            const float bn0 = b2[n0], bn1 = b2[n1], bn2 = b2[n2], bn3 = b2[n3];
            #pragma unroll
            for (int q = 0; q < 4; q++) {
                s_h2[mbase + q][n0] = fmaxf(acc0[q] + bn0, 0.f);
                s_h2[mbase + q][n1] = fmaxf(acc1[q] + bn1, 0.f);
                s_h2[mbase + q][n2] = fmaxf(acc2[q] + bn2, 0.f);
                s_h2[mbase + q][n3] = fmaxf(acc3[q] + bn3, 0.f);
            }
        }
        __syncthreads();

        // E: layer3 (128 -> 3) + sigmoid + weighted accumulate
        if (t < TP*3) {
            int p = t / 3, c = t - 3*p;
            float acc = b3[c];
            for (int k = 0; k < FCH; k++)
                acc = fmaf(s_h2[p][k], w3[k*3 + c], acc);
            float rgb = 1.0f / (1.0f + expf(-acc));
            s_partial[t] += s_wts[s0 + p] * rgb;
        }
        __syncthreads();
    }

    if (t < 3) {
        float sum = 0.f;
        #pragma unroll
        for (int p = 0; p < TP; p++) sum += s_partial[p*3 + t];
        out[r*3 + t] = sum;
    }
}

// ---- fallback (f32 VALU, no workspace) — proven R4 baseline path ------------
__global__ __launch_bounds__(128)
void nerf_render_f32(const float* __restrict__ xyz,
                     const float* __restrict__ viewdirs,
                     const float* __restrict__ dists,
                     const float* __restrict__ dgrid,
                     const float* __restrict__ agrid,
                     const float* __restrict__ w1,
                     const float* __restrict__ b1,
                     const float* __restrict__ w2,
                     const float* __restrict__ b2,
                     const float* __restrict__ w3,
                     const float* __restrict__ b3,
                     float* __restrict__ out)
{
    __shared__ int   s_base[NSAMP];
    __shared__ float s_w8[NSAMP][8];
    __shared__ float s_wts[NSAMP];
    __shared__ float s_vrow[40];
    __shared__ float S_in[16][392];
    __shared__ float s_h1[16][FCH];
    __shared__ float s_partial[16*3];
    __shared__ float s_scanw0;
    float (* const s_h2)[FCH] = reinterpret_cast<float (*)[FCH]>(&S_in[0][0]);

    const int r = blockIdx.x, t = threadIdx.x, lane = t & 63;
    if (t < 48) s_partial[t] = 0.f;
    {
        const int s = t;
        const float px = xyz[(r*NSAMP + s)*3 + 0];
        const float py = xyz[(r*NSAMP + s)*3 + 1];
        const float pz = xyz[(r*NSAMP + s)*3 + 2];
        float fx = (px + 1.0f) * 63.5f, fy = (py + 1.0f) * 63.5f, fz = (pz + 1.0f) * 63.5f;
        int x0 = (int)floorf(fx); x0 = min(max(x0, 0), GSZ-2);
        int y0 = (int)floorf(fy); y0 = min(max(y0, 0), GSZ-2);
        int z0 = (int)floorf(fz); z0 = min(max(z0, 0), GSZ-2);
        float wx = fx - x0, wy = fy - y0, wz = fz - z0;
        float ux = 1.f - wx, uy = 1.f - wy, uz = 1.f - wz;
        int base = (z0*GSZ + y0)*GSZ + x0;
        s_base[s] = base;
        float w000 = uz*uy*ux, w001 = uz*uy*wx, w010 = uz*wy*ux, w011 = uz*wy*wx;
        float w100 = wz*uy*ux, w101 = wz*uy*wx, w110 = wz*wy*ux, w111 = wz*wy*wx;
        s_w8[s][0]=w000; s_w8[s][1]=w001; s_w8[s][2]=w010; s_w8[s][3]=w011;
        s_w8[s][4]=w100; s_w8[s][5]=w101; s_w8[s][6]=w110; s_w8[s][7]=w111;
        const float* dg = dgrid + base;
        float dsum = w000*dg[0]+w001*dg[1]+w010*dg[GSZ]+w011*dg[GSZ+1]
                   + w100*dg[GSZ*GSZ]+w101*dg[GSZ*GSZ+1]
                   + w110*dg[GSZ*GSZ+GSZ]+w111*dg[GSZ*GSZ+GSZ+1];
        float sf = dsum - 10.0f;
        float sigma = fmaxf(sf, 0.f) + log1pf(expf(-fabsf(sf)));
        float alpha = 1.f - expf(-sigma * dists[r*NSAMP + s] * 25.0f);
        float v = 1.f - alpha + 1e-10f;
        float scan = v;
        #pragma unroll
        for (int off = 1; off < 64; off <<= 1) {
            float o = __shfl_up(scan, off, 64);
            if (lane >= off) scan *= o;
        }
        if (t == 63) s_scanw0 = scan;
        __syncthreads();
        float prev = __shfl_up(scan, 1, 64);
        float excl;
        if (t < 64) excl = (lane == 0) ? 1.0f : prev;
        else        excl = (lane == 0) ? s_scanw0 : prev * s_scanw0;
        s_wts[s] = alpha * excl;
    }
    if (t < 21) {
        if (t < 3) s_vrow[t] = viewdirs[r*3 + t];
        else {
            int i = t - 3, d = i / 6, f = i - 6*d;
            float sv, cv;
            sincosf(viewdirs[r*3 + d] * (float)(1 << f), &sv, &cv);
            s_vrow[3 + i] = sv; s_vrow[21 + i] = cv;
        }
    }
    __syncthreads();
    for (int s0 = 0; s0 < NSAMP; s0 += 16) {
        for (int idx = t; idx < 16*APPC; idx += 128) {
            int p = idx / APPC, c = idx - p*APPC, s = s0 + p;
            const float* ag = agrid + (size_t)c*VOX + s_base[s];
            const float* w8 = s_w8[s];
            S_in[p][c] = w8[0]*ag[0]+w8[1]*ag[1]+w8[2]*ag[GSZ]+w8[3]*ag[GSZ+1]
                       + w8[4]*ag[GSZ*GSZ]+w8[5]*ag[GSZ*GSZ+1]
                       + w8[6]*ag[GSZ*GSZ+GSZ]+w8[7]*ag[GSZ*GSZ+GSZ+1];
        }
        for (int idx = t; idx < 16*39; idx += 128) {
            int p = idx / 39, j = idx - p*39;
            S_in[p][(j < 3) ? (27 + j) : (351 + j)] = s_vrow[j];
        }
        __syncthreads();
        for (int idx = t; idx < 16*162; idx += 128) {
            int p = idx / 162, rem = idx - p*162;
            int d = rem / 6, f = rem - 6*d;
            float sv, cv;
            __sincosf(S_in[p][d] * (float)(1 << f), &sv, &cv);
            S_in[p][30 + rem] = sv; S_in[p][192 + rem] = cv;
        }
        __syncthreads();
        {
            const int j = t; float acc[16]; const float bj = b1[j];
            #pragma unroll
            for (int p = 0; p < 16; p++) acc[p] = bj;
            for (int k = 0; k < INW; k += 2) {
                float wk0 = w1[k*FCH + j], wk1 = w1[(k+1)*FCH + j];
                #pragma unroll
                for (int p = 0; p < 16; p++)
                    acc[p] = fmaf(S_in[p][k+1], wk1, fmaf(S_in[p][k], wk0, acc[p]));
            }
            #pragma unroll
            for (int p = 0; p < 16; p++) s_h1[p][j] = fmaxf(acc[p], 0.f);
        }
        __syncthreads();
        {
            const int j = t; float acc[16]; const float bj = b2[j];
            #pragma unroll
            for (int p = 0; p < 16; p++) acc[p] = bj;
            for (int k = 0; k < FCH; k += 2) {
                float wk0 = w2[k*FCH + j], wk1 = w2[(k+1)*FCH + j];
                #pragma unroll
                for (int p = 0; p < 16; p++)
                    acc[p] = fmaf(s_h1[p][k+1], wk1, fmaf(s_h1[p][k], wk0, acc[p]));
            }
            #pragma unroll
            for (int p = 0; p < 16; p++) s_h2[p][j] = fmaxf(acc[p], 0.f);
        }
        __syncthreads();
        if (t < 48) {
            int p = t / 3, c = t - 3*p;
            float acc = b3[c];
            for (int k = 0; k < FCH; k++) acc = fmaf(s_h2[p][k], w3[k*3 + c], acc);
            s_partial[t] += s_wts[s0 + p] / (1.0f + expf(-acc));
        }
        __syncthreads();
    }
    if (t < 3) {
        float sum = 0.f;
        #pragma unroll
        for (int p = 0; p < 16; p++) sum += s_partial[p*3 + t];
        out[r*3 + t] = sum;
    }
}

extern "C" void kernel_launch(void* const* d_in, const int* in_sizes, int n_in,
                              void* d_out, int out_size, void* d_ws, size_t ws_size,
                              hipStream_t stream) {
    const float* xyz      = (const float*)d_in[0];
    const float* viewdirs = (const float*)d_in[1];
    const float* dists    = (const float*)d_in[2];
    const float* dgrid    = (const float*)d_in[3];
    const float* agrid    = (const float*)d_in[4];
    const float* w1       = (const float*)d_in[5];
    const float* b1       = (const float*)d_in[6];
    const float* w2       = (const float*)d_in[7];
    const float* b2       = (const float*)d_in[8];
    const float* w3       = (const float*)d_in[9];
    const float* b3       = (const float*)d_in[10];
    float* out = (float*)d_out;

    const size_t need = (size_t)VOX * VOXPAD * sizeof(ushort);  // 128 MiB
    if (ws_size >= need) {
        ushort* agT = (ushort*)d_ws;
        hipLaunchKernelGGL(transpose_app, dim3(VOX/256), dim3(256), 0, stream,
                           agrid, agT);
        hipLaunchKernelGGL(nerf_render_mfma, dim3(NRAYS), dim3(256), 0, stream,
                           xyz, viewdirs, dists, dgrid, agT,
                           w1, b1, w2, b2, w3, b3, out);
    } else {
        hipLaunchKernelGGL(nerf_render_f32, dim3(NRAYS), dim3(128), 0, stream,
                           xyz, viewdirs, dists, dgrid, agrid,
                           w1, b1, w2, b2, w3, b3, out);
    }
}